// Round 10
// baseline (865.440 us; speedup 1.0000x reference)
//
#include <hip/hip_runtime.h>
#include <stdint.h>

// LeadLagSignature: depth-3 signature of lead-lag path over sliding 16-patches.
// Increments alternate (Delta,0)/(0,Delta) -> half-sparse Chen updates.
// R9 RESTRUCTURE: the recurrence is separable in r (each slice s1[r],s2[r],
// s3[r][:] is self-contained). One BLOCK per position; each of its 4 waves
// owns ONE r-group -> 19 accumulator floats/wave instead of 72 -> natural
// VGPR demand ~50 -> 8 waves/SIMD (32/CU) vs the old shape's 2-3/SIMD at
// ~160 VGPR (uncappable: R7's 128-cap forced AGPR-split, 1.8x slower).
// Occupancy is the one residual lever: R6 (SW pipelining) and R8 (DS-read
// removal) were both neutral; store drain needs more resident waves to hide.
// Carried wins: R3 barrier-free (LDS wave-private; lgkmcnt(0) fences only),
// R4 LDS transpose (stride-20, conflict-free b128) -> 1KB contiguous stores,
// R5 S3 cached streaming (6.5 TB/s fill path, no RFO; nt slower), S2 nt.
// Delta buffer overlays the stage buffer (main-loop-idle) -> 20KB LDS/block
// = exactly 8 blocks/CU.
// (R10 = R9 resubmit: R9 bench failed on container infra, not the kernel.)

#define SEQ   8192
#define IND   8
#define NM    15     // number of Delta rows per patch

typedef float f32x4 __attribute__((ext_vector_type(4)));

__global__ __launch_bounds__(256, 8)
void LeadLagSignature_48361331753748_kernel(const float* __restrict__ x,
                                            float* __restrict__ out)
{
    __shared__ float stage[4][64 * 20];   // 5KB/wave; deltas overlay floats 0..119
    const int tid = threadIdx.x;
    const int r   = tid >> 6;        // wave id == accumulator row-group
    const int L   = tid & 63;
    const int i   = blockIdx.x;      // output position (one per block)
    const int h   = L >> 4;
    const int b   = L & 15;
    const int bm  = b & 7;
    const float maskLo = (b < 8) ? 1.0f : 0.0f;
    const float maskHi = 1.0f - maskLo;
    // Wave-uniform r-dependent constants (hoisted; select u-step vs v-step
    // placement of the dx-terms for this r-group).
    const float uAct  = (r < 2) ? 1.0f : 0.0f;   // dx-term lives in u-step
    const float vAct  = 1.0f - uAct;             // ... or in v-step
    const float SIXTH = 0.16666666666666666f;
    const float ku6 = uAct * SIXTH, ku5 = uAct * 0.5f;
    const float kv6 = vAct * SIXTH, kv5 = vAct * 0.5f;
    const int dhOff = h + 4 * (r & 1);           // this group's w[a] channel

    // Stage Deltas (wave-private; 120 floats at the head of this wave's stage
    // buffer -- stage is not used until the epilogue, and same-wave DS ordering
    // protects the overlap). No __syncthreads anywhere in the kernel.
    float* dbuf = stage[r];
    #pragma unroll
    for (int q = 0; q < 2; ++q) {
        int idx = L + q * 64;
        if (idx < NM * 8) {
            int m = idx >> 3, c = idx & 7;
            int r1 = i + m - 14;   // row of patch[m+1]
            int r0 = i + m - 15;   // row of patch[m]
            float v1 = (r1 >= 0) ? x[r1 * IND + c] : 0.0f;
            float v0 = (r0 >= 0) ? x[r0 * IND + c] : 0.0f;
            dbuf[idx] = v1 - v0;
        }
    }
    asm volatile("s_waitcnt lgkmcnt(0)" ::: "memory");
    __builtin_amdgcn_sched_barrier(0);

    float s1 = 0.f, s2 = 0.f;
    float s3[16];
    #pragma unroll
    for (int c = 0; c < 16; ++c) s3[c] = 0.f;

    for (int m = 0; m < NM; ++m) {
        const float* dm = dbuf + m * 8;
        const float4 lo = *(const float4*)(dm);      // broadcast, 16B aligned
        const float4 hi = *(const float4*)(dm + 4);
        const float dhr = dm[dhOff];    // w[a] for this lane's row
        const float dbr = dm[bm];       // Delta[b mod 8]
        const float d[8] = {lo.x, lo.y, lo.z, lo.w, hi.x, hi.y, hi.z, hi.w};

        // ---- u-step: w = (Delta, 0); active c = 0..7 ----
        {
            const float wb = dbr * maskLo;
            float t  = fmaf(ku6, dhr, 0.5f * s1);
            float c0 = fmaf(wb, t, s2);
            #pragma unroll
            for (int c = 0; c < 8; ++c)
                s3[c] = fmaf(c0, d[c], s3[c]);
            s2 = fmaf(wb, fmaf(ku5, dhr, s1), s2);
            s1 = fmaf(uAct, dhr, s1);
        }
        // ---- v-step: w = (0, Delta); active c = 8..15 ----
        {
            const float wb = dbr * maskHi;
            float t  = fmaf(kv6, dhr, 0.5f * s1);
            float c0 = fmaf(wb, t, s2);
            #pragma unroll
            for (int c = 0; c < 8; ++c)
                s3[8 + c] = fmaf(c0, d[c], s3[8 + c]);
            s2 = fmaf(wb, fmaf(kv5, dhr, s1), s2);
            s1 = fmaf(vAct, dhr, s1);
        }
    }

    // ---- epilogue. Outputs concatenated: [SEQ,16][SEQ,256][SEQ,4096] ----
    const int o1 = i * 16;
    const int o2 = SEQ * 16 + i * 256;
    const long o3 = (long)SEQ * (16 + 256) + (long)i * 4096;

    // S2: wave r covers flat indices 64r + L (= (h+4r)*16 + b). nt, 256B/wave,
    // the block's 4 waves tile the full 1KB line.
    __builtin_nontemporal_store(s2, out + o2 + 64 * r + L);
    // S1: 4 lanes/wave (b==0), scattered 4B cached stores.
    if (b == 0)
        out[o1 + 4 * r + h] = s1;

    // S3: wave-private LDS transpose of this wave's single r-tile ->
    // contiguous 1KB CACHED stores (full-line streaming path, no RFO).
    // Overwrites the delta region -- safe: same-wave DS ops are in-order.
    float* st = stage[r];
    f32x4* wp = (f32x4*)(st + L * 20);   // padded rows: conflict-free b128
    wp[0] = (f32x4){ s3[0],  s3[1],  s3[2],  s3[3]  };
    wp[1] = (f32x4){ s3[4],  s3[5],  s3[6],  s3[7]  };
    wp[2] = (f32x4){ s3[8],  s3[9],  s3[10], s3[11] };
    wp[3] = (f32x4){ s3[12], s3[13], s3[14], s3[15] };
    asm volatile("s_waitcnt lgkmcnt(0)" ::: "memory");
    __builtin_amdgcn_sched_barrier(0);
    #pragma unroll
    for (int j = 0; j < 4; ++j) {
        f32x4 v = *(const f32x4*)(st + (16 * j + (L >> 2)) * 20 + 4 * (L & 3));
        *(f32x4*)(out + o3 + 1024 * r + 256 * j + 4 * L) = v;
    }
    // no trailing fence: buffer not reused (single r-tile per wave)
}

extern "C" void kernel_launch(void* const* d_in, const int* in_sizes, int n_in,
                              void* d_out, int out_size, void* d_ws, size_t ws_size,
                              hipStream_t stream) {
    (void)in_sizes; (void)n_in; (void)d_ws; (void)ws_size; (void)out_size;
    const float* x = (const float*)d_in[0];
    float* out = (float*)d_out;
    dim3 grid(SEQ);          // one block per position
    dim3 block(256);         // 4 waves = 4 r-groups
    hipLaunchKernelGGL(LeadLagSignature_48361331753748_kernel, grid, block, 0, stream,
                       x, out);
}

// Round 11
// 481.515 us; speedup vs baseline: 1.7973x; 1.7973x over previous
//
#include <hip/hip_runtime.h>
#include <stdint.h>

// LeadLagSignature: depth-3 signature of lead-lag path over sliding 16-patches.
// Increments alternate (Delta,0)/(0,Delta) -> half-sparse Chen updates.
// R9 RESTRUCTURE: recurrence is separable in r (each slice s1[r],s2[r],s3[r][:]
// self-contained). One BLOCK per position; each of its 4 waves owns ONE
// r-group -> 19 accumulator floats/wave instead of 72 -> slim waves that can
// reach 8 waves/SIMD, vs the fat shape's 2-3/SIMD at ~160 VGPR.
// R10 LESSON: launch_bounds(256,8) HARD-CAPPED VGPRs at 64 -> compiler spilled
// s3 to SCRATCH (VGPR=32, FETCH 1.4GB, WRITE 2GB, 843us). Min-waves is a cap,
// not a request. R11: (256,4) -> cap 128, natural demand ~56 -> allocator
// lands ~56-64 real VGPRs and occupancy reaches 8/SIMD on its own.
// Carried wins: R3 barrier-free (LDS wave-private; lgkmcnt(0) fences only),
// R4 LDS transpose (stride-20, conflict-free b128) -> 1KB contiguous stores,
// R5 S3 cached streaming (6.5 TB/s fill path, no RFO; nt slower), S2 nt.
// Delta buffer overlays the stage buffer (main-loop-idle) -> 20KB LDS/block
// = exactly 8 blocks/CU.

#define SEQ   8192
#define IND   8
#define NM    15     // number of Delta rows per patch

typedef float f32x4 __attribute__((ext_vector_type(4)));

__global__ __launch_bounds__(256, 4)
void LeadLagSignature_48361331753748_kernel(const float* __restrict__ x,
                                            float* __restrict__ out)
{
    __shared__ float stage[4][64 * 20];   // 5KB/wave; deltas overlay floats 0..119
    const int tid = threadIdx.x;
    const int r   = tid >> 6;        // wave id == accumulator row-group
    const int L   = tid & 63;
    const int i   = blockIdx.x;      // output position (one per block)
    const int h   = L >> 4;
    const int b   = L & 15;
    const int bm  = b & 7;
    const float maskLo = (b < 8) ? 1.0f : 0.0f;
    const float maskHi = 1.0f - maskLo;
    // Wave-uniform r-dependent constants (hoisted; select u-step vs v-step
    // placement of the dx-terms for this r-group).
    const float uAct  = (r < 2) ? 1.0f : 0.0f;   // dx-term lives in u-step
    const float vAct  = 1.0f - uAct;             // ... or in v-step
    const float SIXTH = 0.16666666666666666f;
    const float ku6 = uAct * SIXTH, ku5 = uAct * 0.5f;
    const float kv6 = vAct * SIXTH, kv5 = vAct * 0.5f;
    const int dhOff = h + 4 * (r & 1);           // this group's w[a] channel

    // Stage Deltas (wave-private; 120 floats at the head of this wave's stage
    // buffer -- stage is not used until the epilogue, and same-wave DS ordering
    // protects the overlap). No __syncthreads anywhere in the kernel.
    float* dbuf = stage[r];
    #pragma unroll
    for (int q = 0; q < 2; ++q) {
        int idx = L + q * 64;
        if (idx < NM * 8) {
            int m = idx >> 3, c = idx & 7;
            int r1 = i + m - 14;   // row of patch[m+1]
            int r0 = i + m - 15;   // row of patch[m]
            float v1 = (r1 >= 0) ? x[r1 * IND + c] : 0.0f;
            float v0 = (r0 >= 0) ? x[r0 * IND + c] : 0.0f;
            dbuf[idx] = v1 - v0;
        }
    }
    asm volatile("s_waitcnt lgkmcnt(0)" ::: "memory");
    __builtin_amdgcn_sched_barrier(0);

    float s1 = 0.f, s2 = 0.f;
    float s3[16];
    #pragma unroll
    for (int c = 0; c < 16; ++c) s3[c] = 0.f;

    for (int m = 0; m < NM; ++m) {
        const float* dm = dbuf + m * 8;
        const float4 lo = *(const float4*)(dm);      // broadcast, 16B aligned
        const float4 hi = *(const float4*)(dm + 4);
        const float dhr = dm[dhOff];    // w[a] for this lane's row
        const float dbr = dm[bm];       // Delta[b mod 8]
        const float d[8] = {lo.x, lo.y, lo.z, lo.w, hi.x, hi.y, hi.z, hi.w};

        // ---- u-step: w = (Delta, 0); active c = 0..7 ----
        {
            const float wb = dbr * maskLo;
            float t  = fmaf(ku6, dhr, 0.5f * s1);
            float c0 = fmaf(wb, t, s2);
            #pragma unroll
            for (int c = 0; c < 8; ++c)
                s3[c] = fmaf(c0, d[c], s3[c]);
            s2 = fmaf(wb, fmaf(ku5, dhr, s1), s2);
            s1 = fmaf(uAct, dhr, s1);
        }
        // ---- v-step: w = (0, Delta); active c = 8..15 ----
        {
            const float wb = dbr * maskHi;
            float t  = fmaf(kv6, dhr, 0.5f * s1);
            float c0 = fmaf(wb, t, s2);
            #pragma unroll
            for (int c = 0; c < 8; ++c)
                s3[8 + c] = fmaf(c0, d[c], s3[8 + c]);
            s2 = fmaf(wb, fmaf(kv5, dhr, s1), s2);
            s1 = fmaf(vAct, dhr, s1);
        }
    }

    // ---- epilogue. Outputs concatenated: [SEQ,16][SEQ,256][SEQ,4096] ----
    const int o1 = i * 16;
    const int o2 = SEQ * 16 + i * 256;
    const long o3 = (long)SEQ * (16 + 256) + (long)i * 4096;

    // S2: wave r covers flat indices 64r + L (= (h+4r)*16 + b). nt, 256B/wave,
    // the block's 4 waves tile the full 1KB line.
    __builtin_nontemporal_store(s2, out + o2 + 64 * r + L);
    // S1: 4 lanes/wave (b==0), scattered 4B cached stores.
    if (b == 0)
        out[o1 + 4 * r + h] = s1;

    // S3: wave-private LDS transpose of this wave's single r-tile ->
    // contiguous 1KB CACHED stores (full-line streaming path, no RFO).
    // Overwrites the delta region -- safe: same-wave DS ops are in-order.
    float* st = stage[r];
    f32x4* wp = (f32x4*)(st + L * 20);   // padded rows: conflict-free b128
    wp[0] = (f32x4){ s3[0],  s3[1],  s3[2],  s3[3]  };
    wp[1] = (f32x4){ s3[4],  s3[5],  s3[6],  s3[7]  };
    wp[2] = (f32x4){ s3[8],  s3[9],  s3[10], s3[11] };
    wp[3] = (f32x4){ s3[12], s3[13], s3[14], s3[15] };
    asm volatile("s_waitcnt lgkmcnt(0)" ::: "memory");
    __builtin_amdgcn_sched_barrier(0);
    #pragma unroll
    for (int j = 0; j < 4; ++j) {
        f32x4 v = *(const f32x4*)(st + (16 * j + (L >> 2)) * 20 + 4 * (L & 3));
        *(f32x4*)(out + o3 + 1024 * r + 256 * j + 4 * L) = v;
    }
    // no trailing fence: buffer not reused (single r-tile per wave)
}

extern "C" void kernel_launch(void* const* d_in, const int* in_sizes, int n_in,
                              void* d_out, int out_size, void* d_ws, size_t ws_size,
                              hipStream_t stream) {
    (void)in_sizes; (void)n_in; (void)d_ws; (void)ws_size; (void)out_size;
    const float* x = (const float*)d_in[0];
    float* out = (float*)d_out;
    dim3 grid(SEQ);          // one block per position
    dim3 block(256);         // 4 waves = 4 r-groups
    hipLaunchKernelGGL(LeadLagSignature_48361331753748_kernel, grid, block, 0, stream,
                       x, out);
}

// Round 12
// 146.503 us; speedup vs baseline: 5.9073x; 3.2867x over previous
//
#include <hip/hip_runtime.h>
#include <stdint.h>

// LeadLagSignature: depth-3 signature of lead-lag path over sliding 16-patches.
// Increments alternate (Delta,0)/(0,Delta) -> half-sparse Chen updates.
// R9 RESTRUCTURE: recurrence is separable in r. One BLOCK per position; each
// of its 4 waves owns ONE r-group -> 19 accumulator floats/wave instead of 72.
// R10/R11 LESSON: the slim m-loop body tempts the compiler into FULL UNROLL
// (15 iters) + deep LDS-read pipelining -> live-range explosion -> scratch
// spill (R11: 650MB FETCH, 1.28GB WRITE, 373us at cap 128). The spill was
// never about static state (~60 floats). FIX: #pragma unroll 1 pins live
// ranges to one iteration; launch_bounds back to the proven-sane (256,2).
// Carried wins: R3 barrier-free (LDS wave-private; lgkmcnt(0) fences only),
// R4 LDS transpose (stride-20, conflict-free b128) -> 1KB contiguous stores,
// R5 S3 cached streaming (6.5 TB/s fill path, no RFO; nt slower), S2 nt.
// Delta buffer overlays the stage buffer (main-loop-idle) -> 20KB LDS/block
// = 8 blocks/CU; slim waves (~60 VGPR) -> 7-8 waves/SIMD naturally.

#define SEQ   8192
#define IND   8
#define NM    15     // number of Delta rows per patch

typedef float f32x4 __attribute__((ext_vector_type(4)));

__global__ __launch_bounds__(256, 2)
void LeadLagSignature_48361331753748_kernel(const float* __restrict__ x,
                                            float* __restrict__ out)
{
    __shared__ float stage[4][64 * 20];   // 5KB/wave; deltas overlay floats 0..119
    const int tid = threadIdx.x;
    const int r   = tid >> 6;        // wave id == accumulator row-group
    const int L   = tid & 63;
    const int i   = blockIdx.x;      // output position (one per block)
    const int h   = L >> 4;
    const int b   = L & 15;
    const int bm  = b & 7;
    const float maskLo = (b < 8) ? 1.0f : 0.0f;
    const float maskHi = 1.0f - maskLo;
    // Wave-uniform r-dependent constants (hoisted; select u-step vs v-step
    // placement of the dx-terms for this r-group).
    const float uAct  = (r < 2) ? 1.0f : 0.0f;   // dx-term lives in u-step
    const float vAct  = 1.0f - uAct;             // ... or in v-step
    const float SIXTH = 0.16666666666666666f;
    const float ku6 = uAct * SIXTH, ku5 = uAct * 0.5f;
    const float kv6 = vAct * SIXTH, kv5 = vAct * 0.5f;
    const int dhOff = h + 4 * (r & 1);           // this group's w[a] channel

    // Stage Deltas (wave-private; 120 floats at the head of this wave's stage
    // buffer -- stage is not used until the epilogue, and same-wave DS ordering
    // protects the overlap). No __syncthreads anywhere in the kernel.
    float* dbuf = stage[r];
    #pragma unroll
    for (int q = 0; q < 2; ++q) {
        int idx = L + q * 64;
        if (idx < NM * 8) {
            int m = idx >> 3, c = idx & 7;
            int r1 = i + m - 14;   // row of patch[m+1]
            int r0 = i + m - 15;   // row of patch[m]
            float v1 = (r1 >= 0) ? x[r1 * IND + c] : 0.0f;
            float v0 = (r0 >= 0) ? x[r0 * IND + c] : 0.0f;
            dbuf[idx] = v1 - v0;
        }
    }
    asm volatile("s_waitcnt lgkmcnt(0)" ::: "memory");
    __builtin_amdgcn_sched_barrier(0);

    float s1 = 0.f, s2 = 0.f;
    float s3[16];
    #pragma unroll
    for (int c = 0; c < 16; ++c) s3[c] = 0.f;

    #pragma unroll 1
    for (int m = 0; m < NM; ++m) {
        const float* dm = dbuf + m * 8;
        const float4 lo = *(const float4*)(dm);      // broadcast, 16B aligned
        const float4 hi = *(const float4*)(dm + 4);
        const float dhr = dm[dhOff];    // w[a] for this lane's row
        const float dbr = dm[bm];       // Delta[b mod 8]
        const float d[8] = {lo.x, lo.y, lo.z, lo.w, hi.x, hi.y, hi.z, hi.w};

        // ---- u-step: w = (Delta, 0); active c = 0..7 ----
        {
            const float wb = dbr * maskLo;
            float t  = fmaf(ku6, dhr, 0.5f * s1);
            float c0 = fmaf(wb, t, s2);
            #pragma unroll
            for (int c = 0; c < 8; ++c)
                s3[c] = fmaf(c0, d[c], s3[c]);
            s2 = fmaf(wb, fmaf(ku5, dhr, s1), s2);
            s1 = fmaf(uAct, dhr, s1);
        }
        // ---- v-step: w = (0, Delta); active c = 8..15 ----
        {
            const float wb = dbr * maskHi;
            float t  = fmaf(kv6, dhr, 0.5f * s1);
            float c0 = fmaf(wb, t, s2);
            #pragma unroll
            for (int c = 0; c < 8; ++c)
                s3[8 + c] = fmaf(c0, d[c], s3[8 + c]);
            s2 = fmaf(wb, fmaf(kv5, dhr, s1), s2);
            s1 = fmaf(vAct, dhr, s1);
        }
    }

    // ---- epilogue. Outputs concatenated: [SEQ,16][SEQ,256][SEQ,4096] ----
    const int o1 = i * 16;
    const int o2 = SEQ * 16 + i * 256;
    const long o3 = (long)SEQ * (16 + 256) + (long)i * 4096;

    // S2: wave r covers flat indices 64r + L (= (h+4r)*16 + b). nt, 256B/wave,
    // the block's 4 waves tile the full 1KB line.
    __builtin_nontemporal_store(s2, out + o2 + 64 * r + L);
    // S1: 4 lanes/wave (b==0), scattered 4B cached stores.
    if (b == 0)
        out[o1 + 4 * r + h] = s1;

    // S3: wave-private LDS transpose of this wave's single r-tile ->
    // contiguous 1KB CACHED stores (full-line streaming path, no RFO).
    // Overwrites the delta region -- safe: same-wave DS ops are in-order.
    float* st = stage[r];
    f32x4* wp = (f32x4*)(st + L * 20);   // padded rows: conflict-free b128
    wp[0] = (f32x4){ s3[0],  s3[1],  s3[2],  s3[3]  };
    wp[1] = (f32x4){ s3[4],  s3[5],  s3[6],  s3[7]  };
    wp[2] = (f32x4){ s3[8],  s3[9],  s3[10], s3[11] };
    wp[3] = (f32x4){ s3[12], s3[13], s3[14], s3[15] };
    asm volatile("s_waitcnt lgkmcnt(0)" ::: "memory");
    __builtin_amdgcn_sched_barrier(0);
    #pragma unroll
    for (int j = 0; j < 4; ++j) {
        f32x4 v = *(const f32x4*)(st + (16 * j + (L >> 2)) * 20 + 4 * (L & 3));
        *(f32x4*)(out + o3 + 1024 * r + 256 * j + 4 * L) = v;
    }
    // no trailing fence: buffer not reused (single r-tile per wave)
}

extern "C" void kernel_launch(void* const* d_in, const int* in_sizes, int n_in,
                              void* d_out, int out_size, void* d_ws, size_t ws_size,
                              hipStream_t stream) {
    (void)in_sizes; (void)n_in; (void)d_ws; (void)ws_size; (void)out_size;
    const float* x = (const float*)d_in[0];
    float* out = (float*)d_out;
    dim3 grid(SEQ);          // one block per position
    dim3 block(256);         // 4 waves = 4 r-groups
    hipLaunchKernelGGL(LeadLagSignature_48361331753748_kernel, grid, block, 0, stream,
                       x, out);
}

// Round 13
// 144.720 us; speedup vs baseline: 5.9801x; 1.0123x over previous
//
#include <hip/hip_runtime.h>
#include <stdint.h>

// LeadLagSignature: depth-3 signature of lead-lag path over sliding 16-patches.
// Increments alternate (Delta,0)/(0,Delta) -> half-sparse Chen updates.
// One wave per position; lane owns b=L&15, a in {h,h+4,h+8,h+12}, h=L>>4.
// Input: float32 [8192,8]. Output: float32, concat [8192,16][8192,256][8192,4096].
// FINAL (champion = R5 structure). Session ledger:
//  R3: all __syncthreads removed (LDS wave-private; lgkmcnt(0) fences) + real
//      VGPRs for s3 -> 256->171us. R4: LDS transpose -> 1KB contiguous stores
//      (kills strided-store RFO) -> 149us. R5: S3 CACHED streaming (full-line
//      writes ride the memory-side L3 at fill rate ~6.5 TB/s, no RFO; nt is
//      the SLOWER path) -> 144.4us. Neutral: R6 PPW=2, R8 DS-read removal,
//      R12 slim-wave 8/SIMD occupancy (r-split). Catastrophic: R7/R10 VGPR
//      caps (AGPR-split / scratch spill; natural demand ~160 VGPR at this
//      wave shape -- do not cap below it).
//  Residual ~11us over the 26us write floor is distributed (launch ramp,
//  tail drain, serial compute->store phases); all single-variable levers
//  measured neutral. Practical structural ceiling.

#define SEQ   8192
#define IND   8
#define NM    15     // number of Delta rows per patch
#define WAVES 4

typedef float f32x4 __attribute__((ext_vector_type(4)));

__global__ __launch_bounds__(WAVES * 64, 2)
void LeadLagSignature_48361331753748_kernel(const float* __restrict__ x,
                                            float* __restrict__ out)
{
    __shared__ float dlds[WAVES][NM * 8];
    __shared__ float stage[WAVES][64 * 20];   // 5 KB per wave, wave-private
    const int tid = threadIdx.x;
    const int wv  = tid >> 6;
    const int L   = tid & 63;
    const int i   = blockIdx.x * WAVES + wv;   // output position
    const int h   = L >> 4;
    const int b   = L & 15;
    const int bm  = b & 7;
    const float maskLo = (b < 8) ? 1.0f : 0.0f;
    const float maskHi = 1.0f - maskLo;

    // Stage Deltas: Delta_m[c] = patch[m+1][c] - patch[m][c], patch[p] = xp[i+p]
    // (xp = 15 zero rows then x). 120 values; lanes cover idx and idx+64.
    // Wave-private buffer: no __syncthreads, only intra-wave DS ordering.
    float* dbuf = dlds[wv];
    #pragma unroll
    for (int q = 0; q < 2; ++q) {
        int idx = L + q * 64;
        if (idx < NM * 8) {
            int m = idx >> 3, c = idx & 7;
            int r1 = i + m - 14;   // row of patch[m+1]
            int r0 = i + m - 15;   // row of patch[m]
            float v1 = (r1 >= 0) ? x[r1 * IND + c] : 0.0f;
            float v0 = (r0 >= 0) ? x[r0 * IND + c] : 0.0f;
            dbuf[idx] = v1 - v0;
        }
    }
    asm volatile("s_waitcnt lgkmcnt(0)" ::: "memory");
    __builtin_amdgcn_sched_barrier(0);

    float s1[4] = {0.f, 0.f, 0.f, 0.f};       // S1[h+4r]
    float s2[4] = {0.f, 0.f, 0.f, 0.f};       // S2[h+4r, b]
    float s3[4][16];                          // S3[h+4r, b, :]
    #pragma unroll
    for (int r = 0; r < 4; ++r)
        #pragma unroll
        for (int c = 0; c < 16; ++c) s3[r][c] = 0.f;

    const float SIXTH = 0.16666666666666666f;

    for (int m = 0; m < NM; ++m) {
        const float* dm = dbuf + m * 8;
        const float4 lo = *(const float4*)(dm);      // broadcast, 16B aligned
        const float4 hi = *(const float4*)(dm + 4);
        const float dh  = dm[h];        // Delta[h]   = w[a] for rows h / h+8
        const float dh4 = dm[h + 4];    // Delta[h+4] = w[a] for rows h+4 / h+12
        const float dbr = dm[bm];       // Delta[b mod 8]
        const float d[8] = {lo.x, lo.y, lo.z, lo.w, hi.x, hi.y, hi.z, hi.w};

        // ---- u-step: w = (Delta, 0); active c = 0..7; w[a]!=0 for r=0,1 ----
        {
            const float wb = dbr * maskLo;             // w[b]
            float t0 = fmaf(SIXTH, dh,  0.5f * s1[0]);
            float t1 = fmaf(SIXTH, dh4, 0.5f * s1[1]);
            float c0 = fmaf(wb, t0, s2[0]);
            float c1 = fmaf(wb, t1, s2[1]);
            float c2 = fmaf(wb, 0.5f * s1[2], s2[2]);
            float c3 = fmaf(wb, 0.5f * s1[3], s2[3]);
            #pragma unroll
            for (int c = 0; c < 8; ++c) {
                s3[0][c] = fmaf(c0, d[c], s3[0][c]);
                s3[1][c] = fmaf(c1, d[c], s3[1][c]);
                s3[2][c] = fmaf(c2, d[c], s3[2][c]);
                s3[3][c] = fmaf(c3, d[c], s3[3][c]);
            }
            s2[0] = fmaf(wb, fmaf(0.5f, dh,  s1[0]), s2[0]);
            s2[1] = fmaf(wb, fmaf(0.5f, dh4, s1[1]), s2[1]);
            s2[2] = fmaf(wb, s1[2], s2[2]);
            s2[3] = fmaf(wb, s1[3], s2[3]);
            s1[0] += dh;
            s1[1] += dh4;
        }
        // ---- v-step: w = (0, Delta); active c = 8..15; w[a]!=0 for r=2,3 ----
        {
            const float wb = dbr * maskHi;
            float t2 = fmaf(SIXTH, dh,  0.5f * s1[2]);
            float t3 = fmaf(SIXTH, dh4, 0.5f * s1[3]);
            float c0 = fmaf(wb, 0.5f * s1[0], s2[0]);
            float c1 = fmaf(wb, 0.5f * s1[1], s2[1]);
            float c2 = fmaf(wb, t2, s2[2]);
            float c3 = fmaf(wb, t3, s2[3]);
            #pragma unroll
            for (int c = 0; c < 8; ++c) {
                s3[0][8 + c] = fmaf(c0, d[c], s3[0][8 + c]);
                s3[1][8 + c] = fmaf(c1, d[c], s3[1][8 + c]);
                s3[2][8 + c] = fmaf(c2, d[c], s3[2][8 + c]);
                s3[3][8 + c] = fmaf(c3, d[c], s3[3][8 + c]);
            }
            s2[0] = fmaf(wb, s1[0], s2[0]);
            s2[1] = fmaf(wb, s1[1], s2[1]);
            s2[2] = fmaf(wb, fmaf(0.5f, dh,  s1[2]), s2[2]);
            s2[3] = fmaf(wb, fmaf(0.5f, dh4, s1[3]), s2[3]);
            s1[2] += dh;
            s1[3] += dh4;
        }
    }

    // ---- epilogue. Outputs concatenated: [SEQ,16][SEQ,256][SEQ,4096] ----
    const int o1 = i * 16;
    const int o2 = SEQ * 16 + i * 256;
    const long o3 = (long)SEQ * (16 + 256) + (long)i * 4096;

    // S2: lane-consecutive 4B nt stores (256B contiguous per instr).
    #pragma unroll
    for (int r = 0; r < 4; ++r)
        __builtin_nontemporal_store(s2[r], out + o2 + L + 64 * r);
    // S1: 16 scattered 4B stores per position (512KB region total) - cached.
    if (b == 0) {
        #pragma unroll
        for (int r = 0; r < 4; ++r)
            out[o1 + h + 4 * r] = s1[r];
    }

    // S3: wave-private LDS transpose per r-tile -> contiguous 1KB CACHED stores
    // (full-line coverage; rides the 6.5 TB/s streaming-write path, no RFO).
    float* st = stage[wv];
    #pragma unroll
    for (int r = 0; r < 4; ++r) {
        // write phase: lane L's 16 floats at padded row L*20 (conflict-free b128)
        f32x4* wp = (f32x4*)(st + L * 20);
        wp[0] = (f32x4){ s3[r][0],  s3[r][1],  s3[r][2],  s3[r][3]  };
        wp[1] = (f32x4){ s3[r][4],  s3[r][5],  s3[r][6],  s3[r][7]  };
        wp[2] = (f32x4){ s3[r][8],  s3[r][9],  s3[r][10], s3[r][11] };
        wp[3] = (f32x4){ s3[r][12], s3[r][13], s3[r][14], s3[r][15] };
        asm volatile("s_waitcnt lgkmcnt(0)" ::: "memory");
        __builtin_amdgcn_sched_barrier(0);
        // read phase: lane L covers global floats tile + 256j + 4L (+0..3)
        #pragma unroll
        for (int j = 0; j < 4; ++j) {
            f32x4 v = *(const f32x4*)(st + (16 * j + (L >> 2)) * 20 + 4 * (L & 3));
            *(f32x4*)(out + o3 + 1024 * r + 256 * j + 4 * L) = v;
        }
        asm volatile("s_waitcnt lgkmcnt(0)" ::: "memory");   // WAR: reads done
        __builtin_amdgcn_sched_barrier(0);                   // before reuse
    }
}

extern "C" void kernel_launch(void* const* d_in, const int* in_sizes, int n_in,
                              void* d_out, int out_size, void* d_ws, size_t ws_size,
                              hipStream_t stream) {
    (void)in_sizes; (void)n_in; (void)d_ws; (void)ws_size; (void)out_size;
    const float* x = (const float*)d_in[0];
    float* out = (float*)d_out;
    dim3 grid(SEQ / WAVES);
    dim3 block(WAVES * 64);
    hipLaunchKernelGGL(LeadLagSignature_48361331753748_kernel, grid, block, 0, stream,
                       x, out);
}